// Round 12
// baseline (561.439 us; speedup 1.0000x reference)
//
#include <hip/hip_runtime.h>

typedef short short8 __attribute__((ext_vector_type(8)));
typedef float f32x4 __attribute__((ext_vector_type(4)));
typedef unsigned u32x4 __attribute__((ext_vector_type(4)));

#define DD 4096
#define KSL 8         // split-K factor; ks = bid&7 == XCD (A-slab L2 locality)
#define KSLAB 512     // DD/KSL k-rows per block
#define NT 16         // k-tiles of 32 per block
#define NLAYER 15

__device__ __forceinline__ unsigned short f2bf(float f) {
  unsigned u = __float_as_uint(f);
  u += 0x7FFFu + ((u >> 16) & 1u);   // round-to-nearest-even
  return (unsigned short)(u >> 16);
}
__device__ __forceinline__ float bf2f(unsigned short b) {
  return __uint_as_float(((unsigned)b) << 16);
}

// fp32 x [256][4096] -> bf16 h blocked [k>>5][m 256][k&31]
__global__ __launch_bounds__(256) void k_tobf16(const float* __restrict__ x,
                                                unsigned short* __restrict__ h) {
  const size_t e = ((size_t)blockIdx.x * 256 + threadIdx.x) * 8;
  const int m = (int)(e >> 12), n = (int)(e & (DD - 1));
  f32x4 a = *(const f32x4*)(x + e);
  f32x4 b = *(const f32x4*)(x + e + 4);
  short8 v;
#pragma unroll
  for (int j = 0; j < 4; ++j) { v[j] = (short)f2bf(a[j]); v[4 + j] = (short)f2bf(b[j]); }
  *(short8*)(h + (size_t)(n >> 5) * 8192 + m * 32 + (n & 31)) = v;
}

// 4x4 quad transpose across p-lane groups (verified R3-R11)
__device__ __forceinline__ void qtrans(f32x4 v, int p, unsigned& lo, unsigned& hi) {
  unsigned d0 = (unsigned)f2bf(v[0]) | ((unsigned)f2bf(v[1]) << 16);
  unsigned d1 = (unsigned)f2bf(v[2]) | ((unsigned)f2bf(v[3]) << 16);
  unsigned o0 = (unsigned)__shfl_xor((int)d0, 16);
  unsigned o1 = (unsigned)__shfl_xor((int)d1, 16);
  unsigned r0, r1;
  if ((p & 1) == 0) { r0 = (d0 & 0xFFFFu) | (o0 << 16); r1 = (d0 >> 16) | (o0 & 0xFFFF0000u); }
  else              { r0 = (o1 & 0xFFFFu) | (d1 << 16); r1 = (o1 >> 16) | (d1 & 0xFFFF0000u); }
  unsigned q0 = (unsigned)__shfl_xor((int)r0, 32);
  unsigned q1 = (unsigned)__shfl_xor((int)r1, 32);
  if (p < 2) { lo = r0; hi = q0; } else { lo = q1; hi = r1; }
}

// Split-K GEMM partial (R6 structure) with KSL=8 + M-split:
// block (nblk, mb, ks) = [128 m x 256 n] over k in [ks*512, +512).
// ks = bid&7 == XCD: A-slab fetched once per XCD; mb-pair (bids differing by 8)
// are co-XCD so the second W read is L2-served. 1KB contiguous W per k-row.
__global__ __launch_bounds__(512, 2) void k_gemm(const unsigned short* __restrict__ A,
                                                 const float* __restrict__ W,
                                                 unsigned short* __restrict__ part) {
  __shared__ __align__(16) unsigned char smem[32768];  // 2 x 16KB W-frag buffers
  const int bid  = blockIdx.x;
  const int ks   = bid & 7;          // == XCD under round-robin dispatch
  const int mb   = (bid >> 3) & 1;   // m-half; pair co-XCD -> W L2 reuse
  const int nblk = bid >> 4;         // 0..15
  const int n0   = nblk * 256;
  const int tid  = threadIdx.x;
  const int lane = tid & 63;
  const int wave = tid >> 6;        // 0..7
  const int l15  = lane & 15;
  const int p    = lane >> 4;       // 0..3
  const int pp   = ((p & 1) << 1) | (p >> 1);
  const int nw   = 4 * l15 + pp;    // transposed n-col within 64-strip

  // W staging roles (R6-verified): kg = 8-k group, ns = 64-col strip
  const int kg0 = wave & 3, ns0 = wave >> 2;
  const int kg1 = kg0,      ns1 = ns0 + 2;
  const float* w0 = W + (size_t)(ks * KSLAB + 8 * kg0 + p) * DD + n0 + ns0 * 64 + 4 * l15;
  const float* w1 = W + (size_t)(ks * KSLAB + 8 * kg1 + p) * DD + n0 + ns1 * 64 + 4 * l15;

  // compute decomposition: 2m x 4n waves, wave tile [64 m x 64 n]
  const int wm = wave & 1, wn = wave >> 1;
  const size_t arow = (size_t)(mb * 128 + wm * 64 + l15) * 32 + 8 * p;
  const unsigned short* Ab = A + (size_t)ks * 16 * 8192 + arow;

  const f32x4 fz = {0.f, 0.f, 0.f, 0.f};
  f32x4 acc[4][4];
#pragma unroll
  for (int i = 0; i < 4; ++i)
#pragma unroll
    for (int j = 0; j < 4; ++j) acc[i][j] = fz;

  f32x4 wr[2][4];
  short8 ar[2][4];

#define LOADW(T, S)                                                   \
  do {                                                                \
    const float* s0_ = w0 + (size_t)(T) * 32 * DD;                    \
    const float* s1_ = w1 + (size_t)(T) * 32 * DD;                    \
    wr[S][0] = *(const f32x4*)s0_;                                    \
    wr[S][1] = *(const f32x4*)(s0_ + 4 * DD);                         \
    wr[S][2] = *(const f32x4*)s1_;                                    \
    wr[S][3] = *(const f32x4*)(s1_ + 4 * DD);                         \
  } while (0)

#define LOADA(T, S)                                                   \
  do {                                                                \
    _Pragma("unroll")                                                 \
    for (int mf = 0; mf < 4; ++mf)                                    \
      ar[S][mf] = *(const short8*)(Ab + (size_t)(T) * 8192 + mf * 16 * 32); \
  } while (0)

#define STAGE(S, BUF)                                                 \
  do {                                                                \
    unsigned la, ha, lb, hb;                                          \
    qtrans(wr[S][0], p, la, ha);                                      \
    qtrans(wr[S][1], p, lb, hb);                                      \
    u32x4 v0 = {la, ha, lb, hb};                                      \
    *(u32x4*)(smem + (BUF) * 16384 + kg0 * 4096 + (ns0 * 64 + nw) * 16) = v0; \
    qtrans(wr[S][2], p, la, ha);                                      \
    qtrans(wr[S][3], p, lb, hb);                                      \
    u32x4 v1 = {la, ha, lb, hb};                                      \
    *(u32x4*)(smem + (BUF) * 16384 + kg1 * 4096 + (ns1 * 64 + nw) * 16) = v1; \
  } while (0)

  // prologue
  LOADW(0, 0);
  LOADW(1, 1);
  LOADA(0, 0);
  STAGE(0, 0);
  __syncthreads();

#pragma unroll
  for (int it = 0; it < NT; ++it) {
    if (it + 1 < NT) LOADA(it + 1, (it + 1) & 1);
    if (it + 1 < NT) STAGE((it + 1) & 1, (it + 1) & 1);
    if (it + 2 < NT) LOADW(it + 2, it & 1);
    const unsigned char* bbase = smem + (it & 1) * 16384 + p * 4096 + (wn * 64 + l15) * 16;
#pragma unroll
    for (int nf = 0; nf < 4; ++nf) {
      short8 bf = *(const short8*)(bbase + nf * 256);
#pragma unroll
      for (int mf = 0; mf < 4; ++mf)
        acc[mf][nf] = __builtin_amdgcn_mfma_f32_16x16x32_bf16(ar[it & 1][mf], bf,
                                                              acc[mf][nf], 0, 0, 0);
    }
    __syncthreads();
  }
#undef LOADW
#undef LOADA
#undef STAGE

  // bf16 partial write: pair adjacent cols via lane shuffle, even lanes store u32
  unsigned short* pl = part + (size_t)ks * (256 * 4096);
#pragma unroll
  for (int mf = 0; mf < 4; ++mf)
#pragma unroll
    for (int nf = 0; nf < 4; ++nf) {
      f32x4 a = acc[mf][nf], o;
#pragma unroll
      for (int j = 0; j < 4; ++j) o[j] = __shfl_xor(a[j], 1);
      if ((l15 & 1) == 0) {
        const int col = n0 + wn * 64 + nf * 16 + l15;
        const int rb  = mb * 128 + wm * 64 + mf * 16 + 4 * p;
#pragma unroll
        for (int j = 0; j < 4; ++j) {
          unsigned pk = (unsigned)f2bf(a[j]) | ((unsigned)f2bf(o[j]) << 16);
          *(unsigned*)((char*)pl + ((size_t)(rb + j) * 4096 + col) * 2) = pk;
        }
      }
    }
}

// sum 8 bf16 partials + bias, relu -> bf16 blocked h (+ fp32 out on last layer)
__global__ __launch_bounds__(256) void k_reduce(const unsigned short* __restrict__ part,
                                                const float* __restrict__ bias,
                                                unsigned short* __restrict__ hout,
                                                float* __restrict__ fout) {
  const size_t e = ((size_t)blockIdx.x * 256 + threadIdx.x) * 8;
  float s[8] = {0.f, 0.f, 0.f, 0.f, 0.f, 0.f, 0.f, 0.f};
#pragma unroll
  for (int ks = 0; ks < KSL; ++ks) {
    short8 v = *(const short8*)(part + (size_t)ks * (256 * 4096) + e);
#pragma unroll
    for (int j = 0; j < 8; ++j) s[j] += bf2f((unsigned short)v[j]);
  }
  const int m = (int)(e >> 12), n = (int)(e & (DD - 1));
#pragma unroll
  for (int j = 0; j < 8; ++j) s[j] = fmaxf(s[j] + bias[n + j], 0.f);
  short8 o;
#pragma unroll
  for (int j = 0; j < 8; ++j) o[j] = (short)f2bf(s[j]);
  *(short8*)(hout + (size_t)(n >> 5) * 8192 + m * 32 + (n & 31)) = o;
  if (fout) {
    f32x4 o0, o1;
#pragma unroll
    for (int j = 0; j < 4; ++j) { o0[j] = s[j]; o1[j] = s[4 + j]; }
    float* dst = fout + e;
    *(f32x4*)dst = o0;
    *(f32x4*)(dst + 4) = o1;
  }
}

extern "C" void kernel_launch(void* const* d_in, const int* in_sizes, int n_in,
                              void* d_out, int out_size, void* d_ws, size_t ws_size,
                              hipStream_t stream) {
  const float* x = (const float*)d_in[0];
  const float* W = (const float*)d_in[1];
  const float* b = (const float*)d_in[2];
  float* out = (float*)d_out;

  char* ws = (char*)d_ws;
  unsigned short* h0 = (unsigned short*)ws;                 // 2 MB bf16 blocked
  unsigned short* h1 = (unsigned short*)(ws + (1 << 21));   // 2 MB
  unsigned short* part = (unsigned short*)(ws + (1 << 22)); // 8 x 2 MB bf16 partials

  k_tobf16<<<512, 256, 0, stream>>>(x, h0);
  unsigned short* hc = h0;
  unsigned short* hn = h1;
  for (int l = 0; l < NLAYER; ++l) {
    const bool last = (l == NLAYER - 1);
    k_gemm<<<256, 512, 0, stream>>>(hc, W + (size_t)l * DD * DD, part);
    k_reduce<<<512, 256, 0, stream>>>(part, b + (size_t)l * DD, hn,
                                      last ? out : nullptr);
    unsigned short* t = hc; hc = hn; hn = t;
  }
}

// Round 13
// 448.932 us; speedup vs baseline: 1.2506x; 1.2506x over previous
//
#include <hip/hip_runtime.h>

typedef short short8 __attribute__((ext_vector_type(8)));
typedef float f32x4 __attribute__((ext_vector_type(4)));
typedef unsigned u32x4 __attribute__((ext_vector_type(4)));

#define DD 4096
#define KSL 8         // split-K; ks = bid&7 == XCD; partials 8 x 2MB bf16
#define KSLAB 512     // k-rows per block
#define NT 16         // k-tiles of 32 per block
#define NLAYER 15

__device__ __forceinline__ unsigned short f2bf(float f) {
  unsigned u = __float_as_uint(f);
  u += 0x7FFFu + ((u >> 16) & 1u);   // round-to-nearest-even
  return (unsigned short)(u >> 16);
}
__device__ __forceinline__ float bf2f(unsigned short b) {
  return __uint_as_float(((unsigned)b) << 16);
}

// fp32 x [256][4096] -> bf16 h blocked [k>>5][m 256][k&31]
__global__ __launch_bounds__(256) void k_tobf16(const float* __restrict__ x,
                                                unsigned short* __restrict__ h) {
  const size_t e = ((size_t)blockIdx.x * 256 + threadIdx.x) * 8;
  const int m = (int)(e >> 12), n = (int)(e & (DD - 1));
  f32x4 a = *(const f32x4*)(x + e);
  f32x4 b = *(const f32x4*)(x + e + 4);
  short8 v;
#pragma unroll
  for (int j = 0; j < 4; ++j) { v[j] = (short)f2bf(a[j]); v[4 + j] = (short)f2bf(b[j]); }
  *(short8*)(h + (size_t)(n >> 5) * 8192 + m * 32 + (n & 31)) = v;
}

// 4x4 quad transpose across p-lane groups (verified R3-R12)
__device__ __forceinline__ void qtrans(f32x4 v, int p, unsigned& lo, unsigned& hi) {
  unsigned d0 = (unsigned)f2bf(v[0]) | ((unsigned)f2bf(v[1]) << 16);
  unsigned d1 = (unsigned)f2bf(v[2]) | ((unsigned)f2bf(v[3]) << 16);
  unsigned o0 = (unsigned)__shfl_xor((int)d0, 16);
  unsigned o1 = (unsigned)__shfl_xor((int)d1, 16);
  unsigned r0, r1;
  if ((p & 1) == 0) { r0 = (d0 & 0xFFFFu) | (o0 << 16); r1 = (d0 >> 16) | (o0 & 0xFFFF0000u); }
  else              { r0 = (o1 & 0xFFFFu) | (d1 << 16); r1 = (o1 >> 16) | (d1 & 0xFFFF0000u); }
  unsigned q0 = (unsigned)__shfl_xor((int)r0, 32);
  unsigned q1 = (unsigned)__shfl_xor((int)r1, 32);
  if (p < 2) { lo = r0; hi = q0; } else { lo = q1; hi = r1; }
}

// Split-K GEMM partial: block (nblk, ks) = [256 m x 128 n] over k in [ks*512, +512).
// KSL=8 (half of R6's partial traffic), BM=256 kept -> each W byte read exactly once.
// ks = bid&7 == XCD: A-slab L2-shared within cohort. W chunk/k-row = 512B.
__global__ __launch_bounds__(512, 2) void k_gemm(const unsigned short* __restrict__ A,
                                                 const float* __restrict__ W,
                                                 unsigned short* __restrict__ part) {
  __shared__ __align__(16) unsigned char smem[16384];  // 2 x 8KB W-frag buffers
  const int bid  = blockIdx.x;
  const int ks   = bid & 7;          // == XCD under round-robin dispatch
  const int nblk = bid >> 3;         // 0..31
  const int n0   = nblk * 128;
  const int tid  = threadIdx.x;
  const int lane = tid & 63;
  const int wave = tid >> 6;         // 0..7
  const int l15  = lane & 15;
  const int p    = lane >> 4;        // 0..3
  const int pp   = ((p & 1) << 1) | (p >> 1);
  const int nw   = 4 * l15 + pp;     // transposed n-col within 64-strip

  // W staging role: one (kg, ns) per wave; kg = 8-k group 0..3, ns = 64-col strip 0..1
  const int kg0 = wave & 3, ns0 = wave >> 2;
  const float* w0 = W + (size_t)(ks * KSLAB + 8 * kg0 + p) * DD + n0 + ns0 * 64 + 4 * l15;

  // compute decomposition: 4m x 2n waves, wave tile [64 m x 64 n]
  const int wm = wave & 3, wn = wave >> 2;
  const size_t arow = (size_t)(wm * 64 + l15) * 32 + 8 * p;
  const unsigned short* Ab = A + (size_t)ks * 16 * 8192 + arow;

  const f32x4 fz = {0.f, 0.f, 0.f, 0.f};
  f32x4 acc[4][4];
#pragma unroll
  for (int i = 0; i < 4; ++i)
#pragma unroll
    for (int j = 0; j < 4; ++j) acc[i][j] = fz;

  f32x4 wr[2][2];      // [slot][rows p, p+4]
  short8 ar[2][4];     // [slot][mf]

#define LOADW(T, S)                                                   \
  do {                                                                \
    const float* s_ = w0 + (size_t)(T) * 32 * DD;                     \
    wr[S][0] = *(const f32x4*)s_;                                     \
    wr[S][1] = *(const f32x4*)(s_ + 4 * DD);                          \
  } while (0)

#define LOADA(T, S)                                                   \
  do {                                                                \
    _Pragma("unroll")                                                 \
    for (int mf = 0; mf < 4; ++mf)                                    \
      ar[S][mf] = *(const short8*)(Ab + (size_t)(T) * 8192 + mf * 16 * 32); \
  } while (0)

#define STAGE(S, BUF)                                                 \
  do {                                                                \
    unsigned la, ha, lb, hb;                                          \
    qtrans(wr[S][0], p, la, ha);                                      \
    qtrans(wr[S][1], p, lb, hb);                                      \
    u32x4 v0 = {la, ha, lb, hb};                                      \
    *(u32x4*)(smem + (BUF) * 8192 + kg0 * 2048 + (ns0 * 64 + nw) * 16) = v0; \
  } while (0)

  // prologue
  LOADW(0, 0);
  LOADW(1, 1);
  LOADA(0, 0);
  STAGE(0, 0);
  __syncthreads();

#pragma unroll
  for (int it = 0; it < NT; ++it) {
    if (it + 1 < NT) LOADA(it + 1, (it + 1) & 1);
    if (it + 1 < NT) STAGE((it + 1) & 1, (it + 1) & 1);
    if (it + 2 < NT) LOADW(it + 2, it & 1);
    const unsigned char* bbase = smem + (it & 1) * 8192 + p * 2048 + (wn * 64 + l15) * 16;
#pragma unroll
    for (int nf = 0; nf < 4; ++nf) {
      short8 bf = *(const short8*)(bbase + nf * 256);
#pragma unroll
      for (int mf = 0; mf < 4; ++mf)
        acc[mf][nf] = __builtin_amdgcn_mfma_f32_16x16x32_bf16(ar[it & 1][mf], bf,
                                                              acc[mf][nf], 0, 0, 0);
    }
    __syncthreads();
  }
#undef LOADW
#undef LOADA
#undef STAGE

  // bf16 partial write: pair adjacent cols via lane shuffle, even lanes store u32
  unsigned short* pl = part + (size_t)ks * (256 * 4096);
#pragma unroll
  for (int mf = 0; mf < 4; ++mf)
#pragma unroll
    for (int nf = 0; nf < 4; ++nf) {
      f32x4 a = acc[mf][nf], o;
#pragma unroll
      for (int j = 0; j < 4; ++j) o[j] = __shfl_xor(a[j], 1);
      if ((l15 & 1) == 0) {
        const int col = n0 + wn * 64 + nf * 16 + l15;
        const int rb  = wm * 64 + mf * 16 + 4 * p;
#pragma unroll
        for (int j = 0; j < 4; ++j) {
          unsigned pk = (unsigned)f2bf(a[j]) | ((unsigned)f2bf(o[j]) << 16);
          *(unsigned*)((char*)pl + ((size_t)(rb + j) * 4096 + col) * 2) = pk;
        }
      }
    }
}

// sum 8 bf16 partials + bias, relu -> bf16 blocked h (+ fp32 out on last layer)
__global__ __launch_bounds__(256) void k_reduce(const unsigned short* __restrict__ part,
                                                const float* __restrict__ bias,
                                                unsigned short* __restrict__ hout,
                                                float* __restrict__ fout) {
  const size_t e = ((size_t)blockIdx.x * 256 + threadIdx.x) * 8;
  float s[8] = {0.f, 0.f, 0.f, 0.f, 0.f, 0.f, 0.f, 0.f};
#pragma unroll
  for (int ks = 0; ks < KSL; ++ks) {
    short8 v = *(const short8*)(part + (size_t)ks * (256 * 4096) + e);
#pragma unroll
    for (int j = 0; j < 8; ++j) s[j] += bf2f((unsigned short)v[j]);
  }
  const int m = (int)(e >> 12), n = (int)(e & (DD - 1));
#pragma unroll
  for (int j = 0; j < 8; ++j) s[j] = fmaxf(s[j] + bias[n + j], 0.f);
  short8 o;
#pragma unroll
  for (int j = 0; j < 8; ++j) o[j] = (short)f2bf(s[j]);
  *(short8*)(hout + (size_t)(n >> 5) * 8192 + m * 32 + (n & 31)) = o;
  if (fout) {
    f32x4 o0, o1;
#pragma unroll
    for (int j = 0; j < 4; ++j) { o0[j] = s[j]; o1[j] = s[4 + j]; }
    float* dst = fout + e;
    *(f32x4*)dst = o0;
    *(f32x4*)(dst + 4) = o1;
  }
}

extern "C" void kernel_launch(void* const* d_in, const int* in_sizes, int n_in,
                              void* d_out, int out_size, void* d_ws, size_t ws_size,
                              hipStream_t stream) {
  const float* x = (const float*)d_in[0];
  const float* W = (const float*)d_in[1];
  const float* b = (const float*)d_in[2];
  float* out = (float*)d_out;

  char* ws = (char*)d_ws;
  unsigned short* h0 = (unsigned short*)ws;                 // 2 MB bf16 blocked
  unsigned short* h1 = (unsigned short*)(ws + (1 << 21));   // 2 MB
  unsigned short* part = (unsigned short*)(ws + (1 << 22)); // 8 x 2 MB bf16 partials

  k_tobf16<<<512, 256, 0, stream>>>(x, h0);
  unsigned short* hc = h0;
  unsigned short* hn = h1;
  for (int l = 0; l < NLAYER; ++l) {
    const bool last = (l == NLAYER - 1);
    k_gemm<<<256, 512, 0, stream>>>(hc, W + (size_t)l * DD * DD, part);
    k_reduce<<<512, 256, 0, stream>>>(part, b + (size_t)l * DD, hn,
                                      last ? out : nullptr);
    unsigned short* t = hc; hc = hn; hn = t;
  }
}

// Round 14
// 436.243 us; speedup vs baseline: 1.2870x; 1.0291x over previous
//
#include <hip/hip_runtime.h>

typedef short short8 __attribute__((ext_vector_type(8)));
typedef float f32x4 __attribute__((ext_vector_type(4)));
typedef unsigned u32x4 __attribute__((ext_vector_type(4)));

#define DD 4096
#define KSL 8         // split-K; ks = bid&7 == XCD; partials 8 x 2MB bf16
#define KSLAB 512     // k-rows per block
#define NT 16         // k-tiles of 32 per block
#define NLAYER 15

__device__ __forceinline__ unsigned short f2bf(float f) {
  unsigned u = __float_as_uint(f);
  u += 0x7FFFu + ((u >> 16) & 1u);   // round-to-nearest-even
  return (unsigned short)(u >> 16);
}
__device__ __forceinline__ float bf2f(unsigned short b) {
  return __uint_as_float(((unsigned)b) << 16);
}

// fp32 x [256][4096] -> bf16 h blocked [k>>5][m 256][k&31]
__global__ __launch_bounds__(256) void k_tobf16(const float* __restrict__ x,
                                                unsigned short* __restrict__ h) {
  const size_t e = ((size_t)blockIdx.x * 256 + threadIdx.x) * 8;
  const int m = (int)(e >> 12), n = (int)(e & (DD - 1));
  f32x4 a = *(const f32x4*)(x + e);
  f32x4 b = *(const f32x4*)(x + e + 4);
  short8 v;
#pragma unroll
  for (int j = 0; j < 4; ++j) { v[j] = (short)f2bf(a[j]); v[4 + j] = (short)f2bf(b[j]); }
  *(short8*)(h + (size_t)(n >> 5) * 8192 + m * 32 + (n & 31)) = v;
}

// 4x4 quad transpose across p-lane groups (verified R3-R13)
__device__ __forceinline__ void qtrans(f32x4 v, int p, unsigned& lo, unsigned& hi) {
  unsigned d0 = (unsigned)f2bf(v[0]) | ((unsigned)f2bf(v[1]) << 16);
  unsigned d1 = (unsigned)f2bf(v[2]) | ((unsigned)f2bf(v[3]) << 16);
  unsigned o0 = (unsigned)__shfl_xor((int)d0, 16);
  unsigned o1 = (unsigned)__shfl_xor((int)d1, 16);
  unsigned r0, r1;
  if ((p & 1) == 0) { r0 = (d0 & 0xFFFFu) | (o0 << 16); r1 = (d0 >> 16) | (o0 & 0xFFFF0000u); }
  else              { r0 = (o1 & 0xFFFFu) | (d1 << 16); r1 = (o1 >> 16) | (d1 & 0xFFFF0000u); }
  unsigned q0 = (unsigned)__shfl_xor((int)r0, 32);
  unsigned q1 = (unsigned)__shfl_xor((int)r1, 32);
  if (p < 2) { lo = r0; hi = q0; } else { lo = q1; hi = r1; }
}

// Split-K GEMM partial (R13 structure): block (nblk, ks) = [256 m x 128 n],
// k in [ks*512,+512). Changes vs R13: depth-3 W register pipeline; DENSE
// partial layout [ks][nblk][256 m][128 nl] (block-contiguous 256KB writes).
__global__ __launch_bounds__(512, 2) void k_gemm(const unsigned short* __restrict__ A,
                                                 const float* __restrict__ W,
                                                 unsigned short* __restrict__ part) {
  __shared__ __align__(16) unsigned char smem[16384];  // 2 x 8KB W-frag buffers
  const int bid  = blockIdx.x;
  const int ks   = bid & 7;          // == XCD under round-robin dispatch
  const int nblk = bid >> 3;         // 0..31
  const int n0   = nblk * 128;
  const int tid  = threadIdx.x;
  const int lane = tid & 63;
  const int wave = tid >> 6;         // 0..7
  const int l15  = lane & 15;
  const int p    = lane >> 4;        // 0..3
  const int pp   = ((p & 1) << 1) | (p >> 1);
  const int nw   = 4 * l15 + pp;     // transposed n-col within 64-strip

  // W staging role: one (kg, ns) per wave; kg = 8-k group 0..3, ns = 64-col strip 0..1
  const int kg0 = wave & 3, ns0 = wave >> 2;
  const float* w0 = W + (size_t)(ks * KSLAB + 8 * kg0 + p) * DD + n0 + ns0 * 64 + 4 * l15;

  // compute decomposition: 4m x 2n waves, wave tile [64 m x 64 n]
  const int wm = wave & 3, wn = wave >> 2;
  const size_t arow = (size_t)(wm * 64 + l15) * 32 + 8 * p;
  const unsigned short* Ab = A + (size_t)ks * 16 * 8192 + arow;

  const f32x4 fz = {0.f, 0.f, 0.f, 0.f};
  f32x4 acc[4][4];
#pragma unroll
  for (int i = 0; i < 4; ++i)
#pragma unroll
    for (int j = 0; j < 4; ++j) acc[i][j] = fz;

  f32x4 wr[3][2];      // depth-3 slots: [slot][rows p, p+4]
  short8 ar[2][4];     // [slot][mf]

#define LOADW(T, S)                                                   \
  do {                                                                \
    const float* s_ = w0 + (size_t)(T) * 32 * DD;                     \
    wr[S][0] = *(const f32x4*)s_;                                     \
    wr[S][1] = *(const f32x4*)(s_ + 4 * DD);                          \
  } while (0)

#define LOADA(T, S)                                                   \
  do {                                                                \
    _Pragma("unroll")                                                 \
    for (int mf = 0; mf < 4; ++mf)                                    \
      ar[S][mf] = *(const short8*)(Ab + (size_t)(T) * 8192 + mf * 16 * 32); \
  } while (0)

#define STAGE(S, BUF)                                                 \
  do {                                                                \
    unsigned la, ha, lb, hb;                                          \
    qtrans(wr[S][0], p, la, ha);                                      \
    qtrans(wr[S][1], p, lb, hb);                                      \
    u32x4 v0 = {la, ha, lb, hb};                                      \
    *(u32x4*)(smem + (BUF) * 8192 + kg0 * 2048 + (ns0 * 64 + nw) * 16) = v0; \
  } while (0)

  // prologue: 3 W tiles issued, A tile 0, stage tile 0 -> buf 0
  LOADW(0, 0);
  LOADW(1, 1);
  LOADW(2, 2);
  LOADA(0, 0);
  STAGE(0, 0);
  __syncthreads();

#pragma unroll
  for (int it = 0; it < NT; ++it) {
    if (it + 1 < NT) LOADA(it + 1, (it + 1) & 1);
    if (it + 1 < NT) STAGE((it + 1) % 3, (it + 1) & 1);   // slot loaded >=2 iters ago
    if (it + 3 < NT) LOADW(it + 3, (it + 3) % 3);         // refill freed slot
    const unsigned char* bbase = smem + (it & 1) * 8192 + p * 2048 + (wn * 64 + l15) * 16;
#pragma unroll
    for (int nf = 0; nf < 4; ++nf) {
      short8 bf = *(const short8*)(bbase + nf * 256);
#pragma unroll
      for (int mf = 0; mf < 4; ++mf)
        acc[mf][nf] = __builtin_amdgcn_mfma_f32_16x16x32_bf16(ar[it & 1][mf], bf,
                                                              acc[mf][nf], 0, 0, 0);
    }
    __syncthreads();
  }
#undef LOADW
#undef LOADA
#undef STAGE

  // DENSE bf16 partial write: block-own region [ks][nblk][256 m][128 nl]
  unsigned short* pl = part + ((size_t)(ks * 32 + nblk)) * (256 * 128);
#pragma unroll
  for (int mf = 0; mf < 4; ++mf)
#pragma unroll
    for (int nf = 0; nf < 4; ++nf) {
      f32x4 a = acc[mf][nf], o;
#pragma unroll
      for (int j = 0; j < 4; ++j) o[j] = __shfl_xor(a[j], 1);
      if ((l15 & 1) == 0) {
        const int nl = wn * 64 + nf * 16 + l15;            // 0..127 block-local
        const int rb = wm * 64 + mf * 16 + 4 * p;
#pragma unroll
        for (int j = 0; j < 4; ++j) {
          unsigned pk = (unsigned)f2bf(a[j]) | ((unsigned)f2bf(o[j]) << 16);
          *(unsigned*)((char*)pl + ((size_t)(rb + j) * 128 + nl) * 2) = pk;
        }
      }
    }
}

// sum 8 bf16 partials (dense blocked layout) + bias, relu -> bf16 blocked h
// (+ fp32 out on last layer)
__global__ __launch_bounds__(256) void k_reduce(const unsigned short* __restrict__ part,
                                                const float* __restrict__ bias,
                                                unsigned short* __restrict__ hout,
                                                float* __restrict__ fout) {
  const size_t e = ((size_t)blockIdx.x * 256 + threadIdx.x) * 8;
  const int m = (int)(e >> 12), n = (int)(e & (DD - 1));
  const int nblk = n >> 7, nl = n & 127;
  const size_t pofs = ((size_t)nblk * 256 + m) * 128 + nl;   // + ks*32*256*128
  float s[8] = {0.f, 0.f, 0.f, 0.f, 0.f, 0.f, 0.f, 0.f};
#pragma unroll
  for (int ks = 0; ks < KSL; ++ks) {
    short8 v = *(const short8*)(part + (size_t)ks * (32 * 256 * 128) + pofs);
#pragma unroll
    for (int j = 0; j < 8; ++j) s[j] += bf2f((unsigned short)v[j]);
  }
  f32x4 b0 = *(const f32x4*)(bias + n);
  f32x4 b1 = *(const f32x4*)(bias + n + 4);
#pragma unroll
  for (int j = 0; j < 4; ++j) {
    s[j]     = fmaxf(s[j] + b0[j], 0.f);
    s[4 + j] = fmaxf(s[4 + j] + b1[j], 0.f);
  }
  short8 o;
#pragma unroll
  for (int j = 0; j < 8; ++j) o[j] = (short)f2bf(s[j]);
  *(short8*)(hout + (size_t)(n >> 5) * 8192 + m * 32 + (n & 31)) = o;
  if (fout) {
    f32x4 o0, o1;
#pragma unroll
    for (int j = 0; j < 4; ++j) { o0[j] = s[j]; o1[j] = s[4 + j]; }
    float* dst = fout + e;
    *(f32x4*)dst = o0;
    *(f32x4*)(dst + 4) = o1;
  }
}

extern "C" void kernel_launch(void* const* d_in, const int* in_sizes, int n_in,
                              void* d_out, int out_size, void* d_ws, size_t ws_size,
                              hipStream_t stream) {
  const float* x = (const float*)d_in[0];
  const float* W = (const float*)d_in[1];
  const float* b = (const float*)d_in[2];
  float* out = (float*)d_out;

  char* ws = (char*)d_ws;
  unsigned short* h0 = (unsigned short*)ws;                 // 2 MB bf16 blocked
  unsigned short* h1 = (unsigned short*)(ws + (1 << 21));   // 2 MB
  unsigned short* part = (unsigned short*)(ws + (1 << 22)); // 8 x 2 MB bf16 partials

  k_tobf16<<<512, 256, 0, stream>>>(x, h0);
  unsigned short* hc = h0;
  unsigned short* hn = h1;
  for (int l = 0; l < NLAYER; ++l) {
    const bool last = (l == NLAYER - 1);
    k_gemm<<<256, 512, 0, stream>>>(hc, W + (size_t)l * DD * DD, part);
    k_reduce<<<512, 256, 0, stream>>>(part, b + (size_t)l * DD, hn,
                                      last ? out : nullptr);
    unsigned short* t = hc; hc = hn; hn = t;
  }
}